// Round 5
// baseline (26265.674 us; speedup 1.0000x reference)
//
#include <hip/hip_runtime.h>

#define NB 128
#define NT 1024
#define TT 1024
#define DI 64
#define DH 512
#define DB 128
#define GZ 2048
#define KZ 576

typedef unsigned short u16;
typedef unsigned int u32;
typedef unsigned long long u64;

#if defined(__has_builtin)
#if __has_builtin(__builtin_amdgcn_fdot2)
#define HAS_FDOT2 1
#endif
#endif

typedef _Float16 half2v __attribute__((ext_vector_type(2)));

__device__ __forceinline__ float bf2f(u16 u) {
  union { u32 i; float f; } v; v.i = ((u32)u) << 16; return v.f;
}
__device__ __forceinline__ float fsig(float x) {
  return __builtin_amdgcn_rcpf(1.f + __expf(-x));
}
__device__ __forceinline__ float ftanh(float x) {
  return 1.f - 2.f * __builtin_amdgcn_rcpf(__expf(2.f * x) + 1.f);
}
// dot of two f16 pairs accumulated into f32
__device__ __forceinline__ float dot2p(u32 w, u32 a, float acc) {
#ifdef HAS_FDOT2
  return __builtin_amdgcn_fdot2(__builtin_bit_cast(half2v, w),
                                __builtin_bit_cast(half2v, a), acc, false);
#else
  half2v hw = __builtin_bit_cast(half2v, w), ha = __builtin_bit_cast(half2v, a);
  acc = fmaf((float)hw.x, (float)ha.x, acc);
  return fmaf((float)hw.y, (float)ha.y, acc);
#endif
}
__device__ __forceinline__ u32 packf16(float x, float y) {
  half2v h; h.x = (_Float16)x; h.y = (_Float16)y;
  return __builtin_bit_cast(u32, h);
}

// ---- ws layout (bytes, 256-aligned) ----
#define O_XPK  256
#define O_WZP  (O_XPK + 16777216)     // x pairs: 128*1024*32 u32
#define O_BBP  (O_WZP + 2359296)      // Wz pairs: 288*2048 u32
#define O_FFP  (O_BBP + 147456)       // bb pairs: 288*128 u32
#define O_BIF  (O_FFP + 524288)       // ff pairs: 4*64*512 u32
#define O_FFB  (O_BIF + 8192)         // bi f32[2048]
#define O_BBBF (O_FFB + 8192)         // ffb f32[4*512]
#define O_HWP  (O_BBBF + 512)         // bbb f32[128]
#define O_HBF  (O_HWP + 2048)         // hw pairs u32[512]
#define WS_NEED ((u64)(O_HBF + 8))    // + hb f32[2]  => ~19.83 MB

// ---------------- dtype detection (validated rounds 3-4) ----------------
__global__ void detect_kernel(const u16* x, const u16* wi, const u16* wh, int* flag) {
  const int l = threadIdx.x;
  int cnt = (((x[2 * l] >> 7) & 0xFF) < 134)
          + (((wi[2 * l] >> 7) & 0xFF) < 134)
          + (((wh[2 * l] >> 7) & 0xFF) < 134);
#pragma unroll
  for (int off = 32; off > 0; off >>= 1) cnt += __shfl_down(cnt, off, 64);
  if (l == 0) *flag = (cnt >= 180) ? 1 : 0;  // 1 = bf16 inputs
}

__device__ __forceinline__ float ldf(int f, const void* s, u32 i) {
  return f ? bf2f(((const u16*)s)[i]) : ((const float*)s)[i];
}

// ---- prep: x -> f16 pair-packed ----
__global__ void px_kernel(const void* xs, const int* __restrict__ flag,
                          u32* __restrict__ xpk) {
  const u32 idx = blockIdx.x * 1024 + threadIdx.x;   // pair index, 4.19M total
  const int f = *flag;
  float a, b;
  if (f) {
    const u32 w = ((const u32*)xs)[idx];
    a = bf2f((u16)(w & 0xffff)); b = bf2f((u16)(w >> 16));
  } else {
    const float2 v = ((const float2*)xs)[idx];
    a = v.x; b = v.y;
  }
  xpk[idx] = packf16(a, b);
}

// ---- prep: Wz pair-packed transpose: wzp[k2][o], k=2k2 from Wi|Wh ----
__global__ void pwz_kernel(const void* Wi, const void* Wh,
                           const int* __restrict__ flag, u32* __restrict__ wzp) {
  const int o = blockIdx.x * 256 + threadIdx.x;   // 0..2047
  const int k2 = blockIdx.y;                      // 0..287
  const int f = *flag;
  float a, b;
  if (k2 < 32) {
    const u32 i = (u32)o * DI + 2 * k2;
    a = ldf(f, Wi, i); b = ldf(f, Wi, i + 1);
  } else {
    const u32 i = (u32)o * DH + 2 * (k2 - 32);
    a = ldf(f, Wh, i); b = ldf(f, Wh, i + 1);
  }
  wzp[(u32)k2 * GZ + o] = packf16(a, b);
}

// ---- prep: backbone pair-packed transpose: bbp[k2][m] ----
__global__ void pbb_kernel(const void* bb, const int* __restrict__ flag,
                           u32* __restrict__ bbp) {
  const int m = threadIdx.x;     // 0..127
  const int k2 = blockIdx.x;     // 0..287
  const int f = *flag;
  const u32 i = (u32)m * KZ + 2 * k2;
  bbp[(u32)k2 * DB + m] = packf16(ldf(f, bb, i), ldf(f, bb, i + 1));
}

// ---- prep: ff pair-packed transpose: ffp[mat][k2][o] ----
__global__ void pff_kernel(const void* f1, const void* f2, const void* ta,
                           const void* tb, const int* __restrict__ flag,
                           u32* __restrict__ ffp) {
  const int o = blockIdx.x * 256 + threadIdx.x;   // 0..511
  const int k2 = blockIdx.y;                      // 0..63
  const int mat = blockIdx.z;                     // 0..3
  const void* s = (mat == 0) ? f1 : (mat == 1) ? f2 : (mat == 2) ? ta : tb;
  const int f = *flag;
  const u32 i = (u32)o * DB + 2 * k2;
  ffp[((u32)mat * 64 + k2) * DH + o] = packf16(ldf(f, s, i), ldf(f, s, i + 1));
}

// ---- prep: small vectors -> f32 (+ head pairs) ----
__global__ void psmall_kernel(const void* bi_s, const void* f1b_s, const void* f2b_s,
                              const void* tab_s, const void* tbb_s, const void* bbb_s,
                              const void* hw_s, const void* hb_s,
                              const int* __restrict__ flag,
                              float* __restrict__ bif, float* __restrict__ ffb,
                              float* __restrict__ bbbf, u32* __restrict__ hwp,
                              float* __restrict__ hbf) {
  const int f = *flag;
  for (int i = threadIdx.x; i < 2048; i += 1024) {
    bif[i] = ldf(f, bi_s, i);
    if (i < 512) {
      ffb[i]        = ldf(f, f1b_s, i);
      ffb[512 + i]  = ldf(f, f2b_s, i);
      ffb[1024 + i] = ldf(f, tab_s, i);
      ffb[1536 + i] = ldf(f, tbb_s, i);
      const int w = i >> 8, pr = i & 255;
      hwp[i] = packf16(ldf(f, hw_s, w * DH + 2 * pr), ldf(f, hw_s, w * DH + 2 * pr + 1));
    }
    if (i < 128) bbbf[i] = ldf(f, bbb_s, i);
    if (i < 2)   hbf[i] = ldf(f, hb_s, i);
  }
}

// ------------------------------ main scan ------------------------------
__global__ __launch_bounds__(NT)
void scan_main(const u32* __restrict__ xpk,  const u32* __restrict__ wzp,
               const u32* __restrict__ bbp,  const u32* __restrict__ ffp,
               const float* __restrict__ bif, const float* __restrict__ ffbv,
               const float* __restrict__ bbbf, const u32* __restrict__ hwp,
               const float* __restrict__ hbf, float* __restrict__ out)
{
  __shared__ __align__(16) u32   zin_pk[288];    // f16 pairs [x | h]
  __shared__ __align__(16) u32   vcat_pk[288];   // f16 pairs [x | h_lstm]
  __shared__ __align__(16) float zred[4 * GZ];   // Z k-slice partials (32 KB)
  __shared__ __align__(16) float bbred[8 * DB];
  __shared__ __align__(16) u32   Fpk[64];        // backbone acts, f16 pairs
  __shared__ __align__(16) float zff[4 * DH];

  const int j = threadIdx.x;
  const int b = blockIdx.x;
  const int s = j >> 8, p = j & 255;     // Z roles (also FF: mat=s, pf=p)
  const int s2 = j >> 7, m = j & 127;    // BB roles

  // hoisted constants
  float bi_i0 = 0.f, bi_i1 = 0.f, bi_g0 = 0.f, bi_g1 = 0.f,
        bi_f0 = 0.f, bi_f1 = 0.f, bi_o0 = 0.f, bi_o1 = 0.f, c0 = 0.f, c1 = 0.f;
  if (j < 256) {
    bi_i0 = bif[2 * j];            bi_i1 = bif[2 * j + 1];
    bi_g0 = bif[DH + 2 * j];       bi_g1 = bif[DH + 2 * j + 1];
    bi_f0 = bif[2 * DH + 2 * j];   bi_f1 = bif[2 * DH + 2 * j + 1];
    bi_o0 = bif[3 * DH + 2 * j];   bi_o1 = bif[3 * DH + 2 * j + 1];
    zin_pk[32 + j] = 0u;           // h0 = 0
  }
  const float ffb0 = ffbv[s * DH + 2 * p];
  const float ffb1 = ffbv[s * DH + 2 * p + 1];
  float bb_b0 = 0.f, bb_b1 = 0.f;
  if (j < 64) { bb_b0 = bbbf[2 * j]; bb_b1 = bbbf[2 * j + 1]; }
  u32 hwreg[4]; float hbr = 0.f;
  const int hw_ = j >> 6, hl = j & 63;
  if (j < 128) {
#pragma unroll
    for (int i = 0; i < 4; ++i) hwreg[i] = hwp[hw_ * 256 + hl + 64 * i];
    hbr = hbf[hw_];
  }
  const u32* xrow = xpk + (size_t)b * TT * 32;

  __syncthreads();

  for (int t = 0; t < TT; ++t) {
    if (j < 32) { const u32 xv = xrow[t * 32 + j]; zin_pk[j] = xv; vcat_pk[j] = xv; }
    __syncthreads();                                   // 1: x + h ready

    // ---- Z: [x|h] @ Wz -> zred, thread owns o in {4p..4p+3, 1024+4p..+3} ----
    {
      float a0 = 0.f, a1 = 0.f, a2 = 0.f, a3 = 0.f,
            a4 = 0.f, a5 = 0.f, a6 = 0.f, a7 = 0.f;
      const u32* wp = wzp + (size_t)(s * 72) * GZ + 4 * p;
      const u32* zp = zin_pk + s * 72;
#pragma unroll 2
      for (int k2 = 0; k2 < 72; k2 += 2) {
        const uint2 ap = *(const uint2*)(zp + k2);
        const uint4 wa0 = *(const uint4*)(wp);
        const uint4 wa1 = *(const uint4*)(wp + 1024);
        const uint4 wb0 = *(const uint4*)(wp + 2048);
        const uint4 wb1 = *(const uint4*)(wp + 3072);
        wp += 4096;
        a0 = dot2p(wa0.x, ap.x, a0); a1 = dot2p(wa0.y, ap.x, a1);
        a2 = dot2p(wa0.z, ap.x, a2); a3 = dot2p(wa0.w, ap.x, a3);
        a4 = dot2p(wa1.x, ap.x, a4); a5 = dot2p(wa1.y, ap.x, a5);
        a6 = dot2p(wa1.z, ap.x, a6); a7 = dot2p(wa1.w, ap.x, a7);
        a0 = dot2p(wb0.x, ap.y, a0); a1 = dot2p(wb0.y, ap.y, a1);
        a2 = dot2p(wb0.z, ap.y, a2); a3 = dot2p(wb0.w, ap.y, a3);
        a4 = dot2p(wb1.x, ap.y, a4); a5 = dot2p(wb1.y, ap.y, a5);
        a6 = dot2p(wb1.z, ap.y, a6); a7 = dot2p(wb1.w, ap.y, a7);
      }
      // lane-contiguous float4 stores: conflict-free
      *(float4*)(zred + s * GZ + 4 * p)        = make_float4(a0, a1, a2, a3);
      *(float4*)(zred + s * GZ + 1024 + 4 * p) = make_float4(a4, a5, a6, a7);
    }
    __syncthreads();                                   // 2: zred ready

    // ---- LSTM gates: thread q<256 owns h pair (2q, 2q+1) ----
    if (j < 256) {
      float zi0 = bi_i0, zi1 = bi_i1, zg0 = bi_g0, zg1 = bi_g1,
            zf0 = bi_f0, zf1 = bi_f1, zo0 = bi_o0, zo1 = bi_o1;
#pragma unroll
      for (int sl = 0; sl < 4; ++sl) {
        const float* zr = zred + sl * GZ + 2 * j;
        const float2 vi = *(const float2*)(zr);
        const float2 vg = *(const float2*)(zr + DH);
        const float2 vf = *(const float2*)(zr + 2 * DH);
        const float2 vo = *(const float2*)(zr + 3 * DH);
        zi0 += vi.x; zi1 += vi.y; zg0 += vg.x; zg1 += vg.y;
        zf0 += vf.x; zf1 += vf.y; zo0 += vo.x; zo1 += vo.y;
      }
      c0 = fmaf(c0, fsig(zf0 + 1.f), ftanh(zi0) * fsig(zg0));
      c1 = fmaf(c1, fsig(zf1 + 1.f), ftanh(zi1) * fsig(zg1));
      vcat_pk[32 + j] = packf16(ftanh(c0) * fsig(zo0), ftanh(c1) * fsig(zo1));
    }
    __syncthreads();                                   // 3: h_lstm ready

    // ---- backbone partials: 8 k-slices x 128 outputs ----
    {
      float acc0 = 0.f, acc1 = 0.f;
      const u32* bp = bbp + (size_t)(s2 * 36) * DB + m;
      const u32* vp = vcat_pk + s2 * 36;
#pragma unroll 3
      for (int k2 = 0; k2 < 36; k2 += 2) {
        const uint2 ap = *(const uint2*)(vp + k2);
        acc0 = dot2p(bp[0],  ap.x, acc0);
        acc1 = dot2p(bp[DB], ap.y, acc1);
        bp += 2 * DB;
      }
      bbred[s2 * DB + m] = acc0 + acc1;
    }
    __syncthreads();                                   // 4: bb partials
    if (j < 64) {
      float r0 = bb_b0, r1 = bb_b1;
#pragma unroll
      for (int sl = 0; sl < 8; ++sl) {
        const float2 v = *(const float2*)(bbred + sl * DB + 2 * j);
        r0 += v.x; r1 += v.y;
      }
      Fpk[j] = packf16(1.7159f * ftanh(0.666f * r0), 1.7159f * ftanh(0.666f * r1));
    }
    __syncthreads();                                   // 5: F ready

    // ---- ff1/ff2/ta/tb: thread (mat=s) owns outputs (2p, 2p+1) ----
    {
      float a0 = 0.f, a1 = 0.f;
      const u32* fp = ffp + (size_t)(s * 64) * DH + 2 * p;
#pragma unroll 4
      for (int k2 = 0; k2 < 64; k2 += 2) {
        const uint2 F2 = *(const uint2*)(Fpk + k2);
        const uint2 wA = *(const uint2*)(fp);
        const uint2 wB = *(const uint2*)(fp + DH);
        fp += 2 * DH;
        a0 = dot2p(wA.x, F2.x, a0); a1 = dot2p(wA.y, F2.x, a1);
        a0 = dot2p(wB.x, F2.y, a0); a1 = dot2p(wB.y, F2.y, a1);
      }
      *(float2*)(zff + s * DH + 2 * p) = make_float2(a0 + ffb0, a1 + ffb1);
    }
    __syncthreads();                                   // 6: zff ready

    // ---- combine -> h_new pair ----
    if (j < 256) {
      const float2 v1 = *(const float2*)(zff + 2 * j);
      const float2 v2 = *(const float2*)(zff + DH + 2 * j);
      const float2 va = *(const float2*)(zff + 2 * DH + 2 * j);
      const float2 vb = *(const float2*)(zff + 3 * DH + 2 * j);
      const float ti0 = fsig(va.x + vb.x), ti1 = fsig(va.y + vb.y);
      const float hn0 = fmaf(ftanh(v1.x), 1.f - ti0, ti0 * ftanh(v2.x));
      const float hn1 = fmaf(ftanh(v1.y), 1.f - ti1, ti1 * ftanh(v2.y));
      zin_pk[32 + j] = packf16(hn0, hn1);
      if (t == TT - 1) {
        float* lp = out + (size_t)NB * TT * 2 + (size_t)b * DH + 2 * j;
        lp[0] = hn0; lp[1] = hn1;
      }
    }
    __syncthreads();                                   // 7: h_new ready

    // ---- head ----
    if (j < 128) {
      float acc = 0.f;
#pragma unroll
      for (int i = 0; i < 4; ++i) acc = dot2p(hwreg[i], zin_pk[32 + hl + 64 * i], acc);
#pragma unroll
      for (int off = 32; off > 0; off >>= 1) acc += __shfl_down(acc, off, 64);
      if (hl == 0) out[((size_t)b * TT + t) * 2 + hw_] = acc + hbr;
    }
  }
}

// ---------------- fallback (round-3 verified, bf16 d_in) ----------------
__device__ __forceinline__ void fma8(float& acc, const uint4 u, const float* v) {
  union { u32 i; float f; } tt;
  tt.i = u.x << 16;          acc = fmaf(tt.f, v[0], acc);
  tt.i = u.x & 0xffff0000u;  acc = fmaf(tt.f, v[1], acc);
  tt.i = u.y << 16;          acc = fmaf(tt.f, v[2], acc);
  tt.i = u.y & 0xffff0000u;  acc = fmaf(tt.f, v[3], acc);
  tt.i = u.z << 16;          acc = fmaf(tt.f, v[4], acc);
  tt.i = u.z & 0xffff0000u;  acc = fmaf(tt.f, v[5], acc);
  tt.i = u.w << 16;          acc = fmaf(tt.f, v[6], acc);
  tt.i = u.w & 0xffff0000u;  acc = fmaf(tt.f, v[7], acc);
}
__global__ __launch_bounds__(256, 1)
void fb_scan(const u16* __restrict__ x,   const u16* __restrict__ Wi,
             const u16* __restrict__ bi,  const u16* __restrict__ Wh,
             const u16* __restrict__ bbW, const u16* __restrict__ bbb,
             const u16* __restrict__ f1W, const u16* __restrict__ f1b,
             const u16* __restrict__ f2W, const u16* __restrict__ f2b,
             const u16* __restrict__ taW, const u16* __restrict__ tab,
             const u16* __restrict__ tbW, const u16* __restrict__ tbb,
             const u16* __restrict__ hW,  const u16* __restrict__ hb,
             float* __restrict__ out)
{
  __shared__ __align__(16) float vcat[DI + DH];
  __shared__ __align__(16) float Fb2[DB];
  __shared__ __align__(16) float fpart[256];
  __shared__ __align__(16) float hprev[DH];
  const int j = threadIdx.x, b = blockIdx.x;
  const int u0 = j, u1 = j + 256;
  float bi_r[8];
#pragma unroll
  for (int k = 0; k < 8; ++k) bi_r[k] = bf2f(bi[j + 256 * k]);
  const float b_f1_0 = bf2f(f1b[u0]), b_f1_1 = bf2f(f1b[u1]);
  const float b_f2_0 = bf2f(f2b[u0]), b_f2_1 = bf2f(f2b[u1]);
  const float b_ta_0 = bf2f(tab[u0]), b_ta_1 = bf2f(tab[u1]);
  const float b_tb_0 = bf2f(tbb[u0]), b_tb_1 = bf2f(tbb[u1]);
  const float b_bb = (j < DB) ? bf2f(bbb[j]) : 0.f;
  float hwr[8]; float hbr = 0.f;
  if (j < 128) {
    const int w = j >> 6, l = j & 63;
#pragma unroll
    for (int q = 0; q < 8; ++q) hwr[q] = bf2f(hW[w * DH + q * 64 + l]);
    hbr = bf2f(hb[w]);
  }
  float c0 = 0.f, c1 = 0.f;
  hprev[u0] = 0.f; hprev[u1] = 0.f;
  const u16* xp = x + (size_t)b * TT * DI;
  __syncthreads();
  for (int t = 0; t < TT; ++t) {
    if (j < DI) vcat[j] = bf2f(xp[t * DI + j]);
    __syncthreads();
    float a[8];
#pragma unroll
    for (int k = 0; k < 8; ++k) a[k] = bi_r[k];
#pragma unroll
    for (int r = 0; r < 8; ++r) {
      const u16* wr = Wi + ((size_t)(j + 256 * r)) * DI;
      float acc = a[r];
#pragma unroll
      for (int kk = 0; kk < DI; kk += 8) fma8(acc, *(const uint4*)(wr + kk), vcat + kk);
      a[r] = acc;
    }
#pragma unroll 1
    for (int kb = 0; kb < DH; kb += 64) {
      float hreg[64];
#pragma unroll
      for (int q = 0; q < 16; ++q)
        *(float4*)(hreg + 4 * q) = *(const float4*)(hprev + kb + 4 * q);
#pragma unroll
      for (int r = 0; r < 8; ++r) {
        const u16* wr = Wh + ((size_t)(j + 256 * r)) * DH + kb;
        float acc = a[r];
#pragma unroll
        for (int cc = 0; cc < 8; ++cc) fma8(acc, *(const uint4*)(wr + 8 * cc), hreg + 8 * cc);
        a[r] = acc;
      }
    }
    {
      const float cn0 = fmaf(c0, fsig(a[4] + 1.f), ftanh(a[0]) * fsig(a[2]));
      const float cn1 = fmaf(c1, fsig(a[5] + 1.f), ftanh(a[1]) * fsig(a[3]));
      c0 = cn0; c1 = cn1;
      vcat[DI + u0] = ftanh(cn0) * fsig(a[6]);
      vcat[DI + u1] = ftanh(cn1) * fsig(a[7]);
    }
    __syncthreads();
    {
      const int mm = j & (DB - 1), pp = j >> 7;
      const u16* br = bbW + (size_t)mm * KZ + pp * 288;
      const float* vs = vcat + pp * 288;
      float s0 = 0.f, s1 = 0.f, s2v = 0.f, s3 = 0.f;
#pragma unroll
      for (int kk = 0; kk < 288; kk += 32) {
        fma8(s0, *(const uint4*)(br + kk), vs + kk);
        fma8(s1, *(const uint4*)(br + kk + 8), vs + kk + 8);
        fma8(s2v, *(const uint4*)(br + kk + 16), vs + kk + 16);
        fma8(s3, *(const uint4*)(br + kk + 24), vs + kk + 24);
      }
      fpart[j] = (s0 + s1) + (s2v + s3);
    }
    __syncthreads();
    if (j < DB) Fb2[j] = 1.7159f * ftanh(0.666f * (b_bb + fpart[j] + fpart[j + DB]));
    __syncthreads();
    {
      float Fr[DB];
#pragma unroll
      for (int q = 0; q < 32; ++q) *(float4*)(Fr + 4 * q) = *(const float4*)(Fb2 + 4 * q);
      const u16* rp[8] = {
        f1W + (size_t)u0 * DB, f1W + (size_t)u1 * DB,
        f2W + (size_t)u0 * DB, f2W + (size_t)u1 * DB,
        taW + (size_t)u0 * DB, taW + (size_t)u1 * DB,
        tbW + (size_t)u0 * DB, tbW + (size_t)u1 * DB };
      float sacc[8] = { b_f1_0, b_f1_1, b_f2_0, b_f2_1, b_ta_0, b_ta_1, b_tb_0, b_tb_1 };
#pragma unroll
      for (int rr = 0; rr < 8; ++rr) {
        float acc = sacc[rr];
        const u16* r = rp[rr];
#pragma unroll
        for (int kk = 0; kk < DB; kk += 8) fma8(acc, *(const uint4*)(r + kk), Fr + kk);
        sacc[rr] = acc;
      }
      const float ti0 = fsig(sacc[4] + sacc[6]);
      const float ti1 = fsig(sacc[5] + sacc[7]);
      hprev[u0] = fmaf(ftanh(sacc[0]), 1.f - ti0, ti0 * ftanh(sacc[2]));
      hprev[u1] = fmaf(ftanh(sacc[1]), 1.f - ti1, ti1 * ftanh(sacc[3]));
    }
    __syncthreads();
    if (j < 128) {
      const int l = j & 63;
      float acc = 0.f;
#pragma unroll
      for (int q = 0; q < 8; ++q) acc = fmaf(hprev[q * 64 + l], hwr[q], acc);
#pragma unroll
      for (int off = 32; off > 0; off >>= 1) acc += __shfl_down(acc, off, 64);
      if (l == 0) out[((size_t)b * TT + t) * 2 + (j >> 6)] = acc + hbr;
    }
  }
  out[(size_t)NB * TT * 2 + (size_t)b * DH + u0] = hprev[u0];
  out[(size_t)NB * TT * 2 + (size_t)b * DH + u1] = hprev[u1];
}

extern "C" void kernel_launch(void* const* d_in, const int* in_sizes, int n_in,
                              void* d_out, int out_size, void* d_ws, size_t ws_size,
                              hipStream_t stream) {
  (void)in_sizes; (void)n_in; (void)out_size;

  if (ws_size >= WS_NEED) {
    char* ws = (char*)d_ws;
    int* flag = (int*)ws;
    detect_kernel<<<dim3(1), dim3(64), 0, stream>>>(
        (const u16*)d_in[0], (const u16*)d_in[1], (const u16*)d_in[3], flag);
    px_kernel<<<dim3(4096), dim3(1024), 0, stream>>>(d_in[0], flag, (u32*)(ws + O_XPK));
    pwz_kernel<<<dim3(8, 288), dim3(256), 0, stream>>>(d_in[1], d_in[3], flag,
                                                       (u32*)(ws + O_WZP));
    pbb_kernel<<<dim3(288), dim3(128), 0, stream>>>(d_in[4], flag, (u32*)(ws + O_BBP));
    pff_kernel<<<dim3(2, 64, 4), dim3(256), 0, stream>>>(d_in[6], d_in[8], d_in[10],
                                                         d_in[12], flag, (u32*)(ws + O_FFP));
    psmall_kernel<<<dim3(1), dim3(1024), 0, stream>>>(
        d_in[2], d_in[7], d_in[9], d_in[11], d_in[13], d_in[5], d_in[14], d_in[15],
        flag, (float*)(ws + O_BIF), (float*)(ws + O_FFB), (float*)(ws + O_BBBF),
        (u32*)(ws + O_HWP), (float*)(ws + O_HBF));

    scan_main<<<dim3(NB), dim3(NT), 0, stream>>>(
        (const u32*)(ws + O_XPK), (const u32*)(ws + O_WZP),
        (const u32*)(ws + O_BBP), (const u32*)(ws + O_FFP),
        (const float*)(ws + O_BIF), (const float*)(ws + O_FFB),
        (const float*)(ws + O_BBBF), (const u32*)(ws + O_HWP),
        (const float*)(ws + O_HBF), (float*)d_out);
  } else {
    fb_scan<<<dim3(NB), dim3(256), 0, stream>>>(
        (const u16*)d_in[0],  (const u16*)d_in[1],  (const u16*)d_in[2],
        (const u16*)d_in[3],  (const u16*)d_in[4],  (const u16*)d_in[5],
        (const u16*)d_in[6],  (const u16*)d_in[7],  (const u16*)d_in[8],
        (const u16*)d_in[9],  (const u16*)d_in[10], (const u16*)d_in[11],
        (const u16*)d_in[12], (const u16*)d_in[13], (const u16*)d_in[14],
        (const u16*)d_in[15], (float*)d_out);
  }
}